// Round 1
// baseline (461.304 us; speedup 1.0000x reference)
//
#include <hip/hip_runtime.h>
#include <stdint.h>

#define CONF_THR 0.6f
#define IOU_THR  0.45f
#define MAX_WH_F 4096.0f
#define TOPK     1024
#define MAX_DET  300
#define NCLS     80
#define ROW      85
#define APB      128   // anchors per block in K1

typedef unsigned int u32;
typedef unsigned long long u64;

__device__ __forceinline__ u32 f2s(float f) {
    u32 b = __float_as_uint(f);
    return b ^ ((u32)((int)b >> 31) | 0x80000000u);
}
__device__ __forceinline__ float s2f(u32 k) {
    u32 b = (k & 0x80000000u) ? (k ^ 0x80000000u) : ~k;
    return __uint_as_float(b);
}

// ---------------- K1: per-anchor score/cls ----------------
__global__ __launch_bounds__(256) void k_score(const float* __restrict__ pred,
        u32* __restrict__ key, u32* __restrict__ cls, int NA) {
#pragma clang fp contract(off)
    int img = blockIdx.y;
    int a0 = blockIdx.x * APB;
    int count = min(APB, NA - a0);
    if (count <= 0) return;
    size_t baseoff = ((size_t)img * NA + a0) * ROW;
    const float* base = pred + baseoff;
    __shared__ __align__(16) float tile[APB * ROW];
    int nfloat = count * ROW;
    if ((baseoff & 3) == 0) {
        int nvec = nfloat >> 2;
        const float4* b4 = (const float4*)base;
        float4* t4 = (float4*)tile;
        for (int i = threadIdx.x; i < nvec; i += blockDim.x) t4[i] = b4[i];
        for (int i = (nvec << 2) + threadIdx.x; i < nfloat; i += blockDim.x)
            tile[i] = base[i];
    } else {
        for (int i = threadIdx.x; i < nfloat; i += blockDim.x) tile[i] = base[i];
    }
    __syncthreads();
    int t = threadIdx.x;
    if (t < count) {
        const float* r = tile + t * ROW;
        float obj = r[4];
        float maxv = -1.0f; int cl = 0;
        for (int j = 0; j < NCLS; ++j) {
            float v = r[5 + j] * obj;
            if (v > maxv) { maxv = v; cl = j; }   // first-max == jnp.argmax
        }
        bool valid = (obj > CONF_THR) && (maxv > CONF_THR);
        float score = valid ? maxv : -1.0f;
        size_t g = (size_t)img * NA + a0 + t;
        key[g] = f2s(score);
        cls[g] = (u32)cl;
    }
}

// ---------------- K2: exact top-1024 (radix select + bitonic) ----------------
__global__ __launch_bounds__(1024) void k_topk(const u32* __restrict__ key,
        u32* __restrict__ top_idx, float* __restrict__ top_score, int NA) {
    int img = blockIdx.x;
    const u32* kb = key + (size_t)img * NA;
    __shared__ u32 hist[256];
    __shared__ int sh_d;
    __shared__ u32 sh_t;
    __shared__ u32 gcnt, tie_base;
    __shared__ u32 wave_tot[16];
    __shared__ u64 skey[TOPK];
    int tid = threadIdx.x;
    u32 prefix = 0, target = TOPK;
    for (int level = 0; level < 4; ++level) {
        int shift = 24 - 8 * level;
        if (tid < 256) hist[tid] = 0;
        __syncthreads();
        for (int idx = tid; idx < NA; idx += 1024) {
            u32 k = kb[idx];
            bool in = (level == 0) || ((k >> (shift + 8)) == prefix);
            if (in) atomicAdd(&hist[(k >> shift) & 0xFFu], 1u);
        }
        __syncthreads();
        if (tid == 0) {
            u32 cum = 0; int d = 255;
            for (; d > 0; --d) {
                if (cum + hist[d] >= target) break;
                cum += hist[d];
            }
            sh_d = d; sh_t = target - cum;
        }
        __syncthreads();
        prefix = (prefix << 8) | (u32)sh_d;
        target = sh_t;
        __syncthreads();
    }
    u32 cutv = prefix;
    u32 R = target;               // take R smallest-index ties (key == cutv)
    if (tid == 0) { gcnt = 0; tie_base = 0; }
    __syncthreads();
    int wid = tid >> 6, lane = tid & 63;
    u64 lanemask = (1ull << lane) - 1ull;
    for (int c0 = 0; c0 < NA; c0 += 1024) {
        int idx = c0 + tid;
        bool inb = idx < NA;
        u32 k = inb ? kb[idx] : 0u;
        bool isg = inb && (k > cutv);
        bool ist = inb && (k == cutv);
        if (isg) {
            u32 p = atomicAdd(&gcnt, 1u);
            skey[p] = ((u64)k << 32) | (u64)(u32)(NA - 1 - idx);
        }
        u64 ball = __ballot(ist);
        if (lane == 0) wave_tot[wid] = (u32)__popcll(ball);
        __syncthreads();
        u32 wbase = 0;
        for (int w = 0; w < wid; ++w) wbase += wave_tot[w];
        u32 rank = tie_base + wbase + (u32)__popcll(ball & lanemask);
        if (ist && rank < R)
            skey[(TOPK - R) + rank] = ((u64)k << 32) | (u64)(u32)(NA - 1 - idx);
        __syncthreads();
        if (tid == 0) {
            u32 tot = 0;
            for (int w = 0; w < 16; ++w) tot += wave_tot[w];
            tie_base += tot;
        }
        __syncthreads();
    }
    // bitonic sort, descending by (score, then smaller idx first)
    for (int k2 = 2; k2 <= TOPK; k2 <<= 1) {
        for (int j = k2 >> 1; j > 0; j >>= 1) {
            int i = tid, ixj = i ^ j;
            if (ixj > i) {
                u64 a = skey[i], b = skey[ixj];
                bool desc = ((i & k2) == 0);
                if ((a < b) == desc) { skey[i] = b; skey[ixj] = a; }
            }
            __syncthreads();
        }
    }
    u64 kk = skey[tid];
    u32 aidx = (u32)(NA - 1) - (u32)(kk & 0xFFFFFFFFull);
    top_idx[img * TOPK + tid] = aidx;
    top_score[img * TOPK + tid] = s2f((u32)(kk >> 32));
}

// ---------------- K3: gather boxes/cls for selected ----------------
__global__ void k_prep(const float* __restrict__ pred, const u32* __restrict__ cls,
        const u32* __restrict__ top_idx,
        float* __restrict__ boxk, float* __restrict__ nmsbox,
        float* __restrict__ clsf, int NA) {
#pragma clang fp contract(off)
    int img = blockIdx.y;
    int t = blockIdx.x * blockDim.x + threadIdx.x;
    if (t >= TOPK) return;
    int g = img * TOPK + t;
    u32 aidx = top_idx[g];
    const float* r = pred + ((size_t)img * NA + aidx) * ROW;
    float cx = r[0], cy = r[1], w = r[2], h = r[3];
    float hw = w * 0.5f, hh = h * 0.5f;
    float x1 = cx - hw, y1 = cy - hh, x2 = cx + hw, y2 = cy + hh;
    u32 c = cls[(size_t)img * NA + aidx];
    float off = (float)c * MAX_WH_F;
    boxk[g * 4 + 0] = x1; boxk[g * 4 + 1] = y1;
    boxk[g * 4 + 2] = x2; boxk[g * 4 + 3] = y2;
    nmsbox[g * 4 + 0] = x1 + off; nmsbox[g * 4 + 1] = y1 + off;
    nmsbox[g * 4 + 2] = x2 + off; nmsbox[g * 4 + 3] = y2 + off;
    clsf[g] = (float)c;
}

// ---------------- K4: 1024x1024 IoU suppression bitmask ----------------
__global__ __launch_bounds__(1024) void k_mask(const float* __restrict__ nmsbox,
        u64* __restrict__ mask) {
#pragma clang fp contract(off)
    int img = blockIdx.y;
    // SoA with +1-per-32 padding: stride-64 accesses land on distinct banks
    __shared__ float bx[TOPK + 32], by[TOPK + 32], bX[TOPK + 32], bY[TOPK + 32], ar[TOPK + 32];
    int tid = threadIdx.x;
    {
        const float4* nb = (const float4*)(nmsbox + (size_t)img * TOPK * 4);
        float4 b = nb[tid];
        int pi = tid + (tid >> 5);
        bx[pi] = b.x; by[pi] = b.y; bX[pi] = b.z; bY[pi] = b.w;
        ar[pi] = (b.z - b.x) * (b.w - b.y);
    }
    __syncthreads();
    int i = blockIdx.x * 64 + (tid >> 4);
    int w = tid & 15;
    int pi = i + (i >> 5);
    float ax = bx[pi], ay = by[pi], aX = bX[pi], aY = bY[pi], aa = ar[pi];
    u64 bits = 0;
    for (int jj = 0; jj < 64; ++jj) {
        int j = (w << 6) + jj;
        if (j > i) {
            int pj = j + (j >> 5);
            float ltx = fmaxf(ax, bx[pj]);
            float lty = fmaxf(ay, by[pj]);
            float rbx = fminf(aX, bX[pj]);
            float rby = fminf(aY, bY[pj]);
            float ww = fmaxf(rbx - ltx, 0.0f);
            float hh = fmaxf(rby - lty, 0.0f);
            float inter = ww * hh;
            float denom = ((aa + ar[pj]) - inter) + 1e-9f;  // exact np expr order
            float iou = inter / denom;
            if (iou > IOU_THR) bits |= (1ull << jj);
        }
    }
    mask[((size_t)img * TOPK + i) * 16 + w] = bits;
}

// ---------------- K5: sequential greedy reduction, 1 wave/image ----------------
__global__ void k_nms(const u64* __restrict__ mask, const float* __restrict__ top_score,
        u32* __restrict__ sel, u32* __restrict__ selcnt) {
    int img = blockIdx.x;
    int lane = threadIdx.x;
    __shared__ float sc[TOPK];
    for (int i = lane; i < TOPK; i += 64) sc[i] = top_score[img * TOPK + i];
    __syncthreads();
    const u64* mrow = mask + (size_t)img * TOPK * 16;
    u64 rem = 0;                                   // lane l<16 owns suppressed word l
    u64 nxt = (lane < 16) ? mrow[lane] : 0ull;
    int kept = 0;
    for (int i = 0; i < TOPK; ++i) {
        u64 row = nxt;
        nxt = (lane < 16 && i + 1 < TOPK) ? mrow[(size_t)(i + 1) * 16 + lane] : 0ull;
        if (!(sc[i] > CONF_THR)) break;            // scores sorted desc -> prefix
        int w = i >> 6, b = i & 63;
        u64 rw = __shfl(rem, w);
        if (!((rw >> b) & 1ull)) {
            if (lane == 0) sel[img * MAX_DET + kept] = (u32)i;
            rem |= row;                            // row has only bits j>i
            ++kept;
            if (kept >= MAX_DET) break;            // only first 300 keeps matter
        }
    }
    if (lane == 0) selcnt[img] = (u32)kept;
}

// ---------------- K6: write all outputs (d_out re-poisoned each launch) ----------------
__global__ void k_out(const float* __restrict__ logits,
        const u32* __restrict__ top_idx, const float* __restrict__ top_score,
        const float* __restrict__ boxk, const float* __restrict__ clsf,
        const u32* __restrict__ sel, const u32* __restrict__ selcnt,
        float* __restrict__ out, int NA, int B) {
    int img = blockIdx.y;
    int t = blockIdx.x;
    int tid = threadIdx.x;
    u32 K = selcnt[img];
    size_t detoff = ((size_t)img * MAX_DET + t) * 6;
    size_t voff = (size_t)B * MAX_DET * 6 + (size_t)img * MAX_DET + t;
    size_t loff = (size_t)B * MAX_DET * 7 + ((size_t)img * MAX_DET + t) * NCLS;
    if ((u32)t < K) {
        int slot = (int)sel[img * MAX_DET + t];
        int g = img * TOPK + slot;
        u32 aidx = top_idx[g];
        if (tid < NCLS)      out[loff + tid] = logits[((size_t)img * NA + aidx) * NCLS + tid];
        else if (tid < 84)   out[detoff + (tid - 80)] = boxk[(size_t)g * 4 + (tid - 80)];
        else if (tid == 84)  out[detoff + 4] = top_score[g];
        else if (tid == 85)  out[detoff + 5] = clsf[g];
        else if (tid == 86)  out[voff] = 1.0f;
    } else {
        if (tid < NCLS)      out[loff + tid] = 0.0f;
        else if (tid < 86)   out[detoff + (tid - 80)] = 0.0f;
        else if (tid == 86)  out[voff] = 0.0f;
    }
}

extern "C" void kernel_launch(void* const* d_in, const int* in_sizes, int n_in,
                              void* d_out, int out_size, void* d_ws, size_t ws_size,
                              hipStream_t stream) {
    const float* pred = (const float*)d_in[0];
    const float* logits = (const float*)d_in[1];
    float* out = (float*)d_out;
    const int B = out_size / (MAX_DET * (6 + 1 + NCLS));   // 16
    const int NA = in_sizes[0] / (B * ROW);                // 25200

    char* p = (char*)d_ws;
    auto alloc = [&](size_t bytes) -> void* {
        void* r = (void*)p;
        p += (bytes + 255) & ~(size_t)255;
        return r;
    };
    u32* key       = (u32*)alloc((size_t)B * NA * 4);
    u32* cls       = (u32*)alloc((size_t)B * NA * 4);
    u32* top_idx   = (u32*)alloc((size_t)B * TOPK * 4);
    float* top_scr = (float*)alloc((size_t)B * TOPK * 4);
    float* boxk    = (float*)alloc((size_t)B * TOPK * 16);
    float* nmsbox  = (float*)alloc((size_t)B * TOPK * 16);
    float* clsf    = (float*)alloc((size_t)B * TOPK * 4);
    u64* mask      = (u64*)alloc((size_t)B * TOPK * 16 * 8);
    u32* sel       = (u32*)alloc((size_t)B * MAX_DET * 4);
    u32* selcnt    = (u32*)alloc((size_t)B * 4);

    k_score<<<dim3((NA + APB - 1) / APB, B), 256, 0, stream>>>(pred, key, cls, NA);
    k_topk<<<dim3(B), 1024, 0, stream>>>(key, top_idx, top_scr, NA);
    k_prep<<<dim3(TOPK / 256, B), 256, 0, stream>>>(pred, cls, top_idx, boxk, nmsbox, clsf, NA);
    k_mask<<<dim3(TOPK / 64, B), 1024, 0, stream>>>(nmsbox, mask);
    k_nms<<<dim3(B), 64, 0, stream>>>(mask, top_scr, sel, selcnt);
    k_out<<<dim3(MAX_DET, B), 128, 0, stream>>>(logits, top_idx, top_scr, boxk, clsf,
                                                sel, selcnt, out, NA, B);
}

// Round 2
// 448.425 us; speedup vs baseline: 1.0287x; 1.0287x over previous
//
#include <hip/hip_runtime.h>
#include <stdint.h>

#define CONF_THR 0.6f
#define IOU_THR  0.45f
#define MAX_WH_F 4096.0f
#define TOPK     1024
#define MAX_DET  300
#define NCLS     80
#define ROW      85
#define APB      128   // anchors per block in K1
#define NMS_P    32    // k_nms prefetch pipeline depth (rows in flight)

typedef unsigned int u32;
typedef unsigned long long u64;

__device__ __forceinline__ u32 f2s(float f) {
    u32 b = __float_as_uint(f);
    return b ^ ((u32)((int)b >> 31) | 0x80000000u);
}
__device__ __forceinline__ float s2f(u32 k) {
    u32 b = (k & 0x80000000u) ? (k ^ 0x80000000u) : ~k;
    return __uint_as_float(b);
}

// ---------------- K1: per-anchor score/cls ----------------
__global__ __launch_bounds__(256) void k_score(const float* __restrict__ pred,
        u32* __restrict__ key, u32* __restrict__ cls, int NA) {
#pragma clang fp contract(off)
    int img = blockIdx.y;
    int a0 = blockIdx.x * APB;
    int count = min(APB, NA - a0);
    if (count <= 0) return;
    size_t baseoff = ((size_t)img * NA + a0) * ROW;
    const float* base = pred + baseoff;
    __shared__ __align__(16) float tile[APB * ROW];
    int nfloat = count * ROW;
    if ((baseoff & 3) == 0) {
        int nvec = nfloat >> 2;
        const float4* b4 = (const float4*)base;
        float4* t4 = (float4*)tile;
        for (int i = threadIdx.x; i < nvec; i += blockDim.x) t4[i] = b4[i];
        for (int i = (nvec << 2) + threadIdx.x; i < nfloat; i += blockDim.x)
            tile[i] = base[i];
    } else {
        for (int i = threadIdx.x; i < nfloat; i += blockDim.x) tile[i] = base[i];
    }
    __syncthreads();
    int t = threadIdx.x;
    if (t < count) {
        const float* r = tile + t * ROW;
        float obj = r[4];
        float maxv = -1.0f; int cl = 0;
        for (int j = 0; j < NCLS; ++j) {
            float v = r[5 + j] * obj;
            if (v > maxv) { maxv = v; cl = j; }   // first-max == jnp.argmax
        }
        bool valid = (obj > CONF_THR) && (maxv > CONF_THR);
        float score = valid ? maxv : -1.0f;
        size_t g = (size_t)img * NA + a0 + t;
        key[g] = f2s(score);
        cls[g] = (u32)cl;
    }
}

// ---------------- K2: exact top-1024 (radix select + bitonic) ----------------
__global__ __launch_bounds__(1024) void k_topk(const u32* __restrict__ key,
        u32* __restrict__ top_idx, float* __restrict__ top_score, int NA) {
    int img = blockIdx.x;
    const u32* kb = key + (size_t)img * NA;
    __shared__ u32 hist[256];
    __shared__ u32 sfx[256];
    __shared__ int sh_d;
    __shared__ u32 sh_t;
    __shared__ u32 gcnt, tie_base;
    __shared__ u32 wave_tot[16];
    __shared__ u64 skey[TOPK];
    int tid = threadIdx.x;
    u32 prefix = 0, target = TOPK;
    for (int level = 0; level < 4; ++level) {
        int shift = 24 - 8 * level;
        if (tid < 256) hist[tid] = 0;
        __syncthreads();
        for (int idx = tid; idx < NA; idx += 1024) {
            u32 k = kb[idx];
            bool in = (level == 0) || ((k >> (shift + 8)) == prefix);
            if (in) atomicAdd(&hist[(k >> shift) & 0xFFu], 1u);
        }
        __syncthreads();
        // parallel suffix-sum over 256 bins: sfx[d] = sum_{k>=d} hist[k]
        if (tid < 256) sfx[tid] = hist[tid];
        __syncthreads();
        for (int off = 1; off < 256; off <<= 1) {
            u32 v = 0;
            if (tid < 256) {
                v = sfx[tid];
                if (tid + off < 256) v += sfx[tid + off];
            }
            __syncthreads();
            if (tid < 256) sfx[tid] = v;
            __syncthreads();
        }
        // reference scan (d descending from 255, break when cum+hist[d]>=target)
        // == largest d with sfx[d] >= target; new target = target - sfx[d+1]
        if (tid < 256) {
            u32 S = sfx[tid];
            u32 Snext = (tid == 255) ? 0u : sfx[tid + 1];
            if (S >= target && Snext < target) { sh_d = tid; sh_t = target - Snext; }
        }
        __syncthreads();
        prefix = (prefix << 8) | (u32)sh_d;
        target = sh_t;
        __syncthreads();
    }
    u32 cutv = prefix;
    u32 R = target;               // take R smallest-index ties (key == cutv)
    if (tid == 0) { gcnt = 0; tie_base = 0; }
    __syncthreads();
    int wid = tid >> 6, lane = tid & 63;
    u64 lanemask = (1ull << lane) - 1ull;
    for (int c0 = 0; c0 < NA; c0 += 1024) {
        int idx = c0 + tid;
        bool inb = idx < NA;
        u32 k = inb ? kb[idx] : 0u;
        bool isg = inb && (k > cutv);
        bool ist = inb && (k == cutv);
        if (isg) {
            u32 p = atomicAdd(&gcnt, 1u);
            skey[p] = ((u64)k << 32) | (u64)(u32)(NA - 1 - idx);
        }
        u64 ball = __ballot(ist);
        if (lane == 0) wave_tot[wid] = (u32)__popcll(ball);
        __syncthreads();
        u32 wbase = 0;
        for (int w = 0; w < wid; ++w) wbase += wave_tot[w];
        u32 rank = tie_base + wbase + (u32)__popcll(ball & lanemask);
        if (ist && rank < R)
            skey[(TOPK - R) + rank] = ((u64)k << 32) | (u64)(u32)(NA - 1 - idx);
        __syncthreads();
        if (tid == 0) {
            u32 tot = 0;
            for (int w = 0; w < 16; ++w) tot += wave_tot[w];
            tie_base += tot;
        }
        __syncthreads();
    }
    // bitonic sort, descending by (score, then smaller idx first)
    for (int k2 = 2; k2 <= TOPK; k2 <<= 1) {
        for (int j = k2 >> 1; j > 0; j >>= 1) {
            int i = tid, ixj = i ^ j;
            if (ixj > i) {
                u64 a = skey[i], b = skey[ixj];
                bool desc = ((i & k2) == 0);
                if ((a < b) == desc) { skey[i] = b; skey[ixj] = a; }
            }
            __syncthreads();
        }
    }
    u64 kk = skey[tid];
    u32 aidx = (u32)(NA - 1) - (u32)(kk & 0xFFFFFFFFull);
    top_idx[img * TOPK + tid] = aidx;
    top_score[img * TOPK + tid] = s2f((u32)(kk >> 32));
}

// ---------------- K3: gather boxes/cls for selected ----------------
__global__ void k_prep(const float* __restrict__ pred, const u32* __restrict__ cls,
        const u32* __restrict__ top_idx,
        float* __restrict__ boxk, float* __restrict__ nmsbox,
        float* __restrict__ clsf, int NA) {
#pragma clang fp contract(off)
    int img = blockIdx.y;
    int t = blockIdx.x * blockDim.x + threadIdx.x;
    if (t >= TOPK) return;
    int g = img * TOPK + t;
    u32 aidx = top_idx[g];
    const float* r = pred + ((size_t)img * NA + aidx) * ROW;
    float cx = r[0], cy = r[1], w = r[2], h = r[3];
    float hw = w * 0.5f, hh = h * 0.5f;
    float x1 = cx - hw, y1 = cy - hh, x2 = cx + hw, y2 = cy + hh;
    u32 c = cls[(size_t)img * NA + aidx];
    float off = (float)c * MAX_WH_F;
    boxk[g * 4 + 0] = x1; boxk[g * 4 + 1] = y1;
    boxk[g * 4 + 2] = x2; boxk[g * 4 + 3] = y2;
    nmsbox[g * 4 + 0] = x1 + off; nmsbox[g * 4 + 1] = y1 + off;
    nmsbox[g * 4 + 2] = x2 + off; nmsbox[g * 4 + 3] = y2 + off;
    clsf[g] = (float)c;
}

// ---------------- K4: 1024x1024 IoU suppression bitmask ----------------
__global__ __launch_bounds__(1024) void k_mask(const float* __restrict__ nmsbox,
        u64* __restrict__ mask) {
#pragma clang fp contract(off)
    int img = blockIdx.y;
    // SoA with +1-per-32 padding: stride-64 accesses land on distinct banks
    __shared__ float bx[TOPK + 32], by[TOPK + 32], bX[TOPK + 32], bY[TOPK + 32], ar[TOPK + 32];
    int tid = threadIdx.x;
    {
        const float4* nb = (const float4*)(nmsbox + (size_t)img * TOPK * 4);
        float4 b = nb[tid];
        int pi = tid + (tid >> 5);
        bx[pi] = b.x; by[pi] = b.y; bX[pi] = b.z; bY[pi] = b.w;
        ar[pi] = (b.z - b.x) * (b.w - b.y);
    }
    __syncthreads();
    int i = blockIdx.x * 64 + (tid >> 4);
    int w = tid & 15;
    int pi = i + (i >> 5);
    float ax = bx[pi], ay = by[pi], aX = bX[pi], aY = bY[pi], aa = ar[pi];
    u64 bits = 0;
    for (int jj = 0; jj < 64; ++jj) {
        int j = (w << 6) + jj;
        if (j > i) {
            int pj = j + (j >> 5);
            float ltx = fmaxf(ax, bx[pj]);
            float lty = fmaxf(ay, by[pj]);
            float rbx = fminf(aX, bX[pj]);
            float rby = fminf(aY, bY[pj]);
            float ww = fmaxf(rbx - ltx, 0.0f);
            float hh = fmaxf(rby - lty, 0.0f);
            float inter = ww * hh;
            float denom = ((aa + ar[pj]) - inter) + 1e-9f;  // exact np expr order
            float iou = inter / denom;
            if (iou > IOU_THR) bits |= (1ull << jj);
        }
    }
    mask[((size_t)img * TOPK + i) * 16 + w] = bits;
}

// ---------------- K5: sequential greedy reduction, 1 wave/image ----------------
// Latency fix: 32-row register prefetch ring (lane w<16 holds word w of each
// row). Per-iter critical path = shfl(rem,w) + bit test; loads 32 deep.
__global__ __launch_bounds__(64) void k_nms(const u64* __restrict__ mask,
        const float* __restrict__ top_score,
        u32* __restrict__ sel, u32* __restrict__ selcnt) {
    int img = blockIdx.x;
    int lane = threadIdx.x;
    const u64* mrow = mask + (size_t)img * TOPK * 16;
    // nvalid = count of scores > CONF_THR (scores sorted desc -> prefix)
    int cnt = 0;
    for (int k = 0; k < TOPK / 64; ++k) {
        float s = top_score[img * TOPK + k * 64 + lane];
        cnt += (s > CONF_THR) ? 1 : 0;
    }
    for (int off = 32; off > 0; off >>= 1) cnt += __shfl_down(cnt, off);
    int nvalid = __shfl(cnt, 0);

    bool ld = lane < 16;
    u64 rem = 0;                       // lane w<16 owns suppressed word w
    u64 buf[NMS_P];
#pragma unroll
    for (int k = 0; k < NMS_P; ++k)
        buf[k] = (ld && k < TOPK) ? mrow[(size_t)k * 16 + lane] : 0ull;
    int kept = 0;
    for (int base = 0; base < TOPK; base += NMS_P) {
        if (base >= nvalid || kept >= MAX_DET) break;
#pragma unroll
        for (int k = 0; k < NMS_P; ++k) {
            int i = base + k;
            u64 roww = buf[k];
            int pf = i + NMS_P;
            buf[k] = (ld && pf < TOPK) ? mrow[(size_t)pf * 16 + lane] : 0ull;
            if (i < nvalid && kept < MAX_DET) {
                int w = i >> 6, b = i & 63;
                u64 rw = __shfl(rem, w);
                if (!((rw >> b) & 1ull)) {
                    if (lane == 0) sel[img * MAX_DET + kept] = (u32)i;
                    rem |= roww;       // roww has only bits j>i
                    ++kept;
                }
            }
        }
    }
    if (lane == 0) selcnt[img] = (u32)kept;
}

// ---------------- K6: write all outputs (d_out re-poisoned each launch) ----------------
__global__ void k_out(const float* __restrict__ logits,
        const u32* __restrict__ top_idx, const float* __restrict__ top_score,
        const float* __restrict__ boxk, const float* __restrict__ clsf,
        const u32* __restrict__ sel, const u32* __restrict__ selcnt,
        float* __restrict__ out, int NA, int B) {
    int img = blockIdx.y;
    int t = blockIdx.x;
    int tid = threadIdx.x;
    u32 K = selcnt[img];
    size_t detoff = ((size_t)img * MAX_DET + t) * 6;
    size_t voff = (size_t)B * MAX_DET * 6 + (size_t)img * MAX_DET + t;
    size_t loff = (size_t)B * MAX_DET * 7 + ((size_t)img * MAX_DET + t) * NCLS;
    if ((u32)t < K) {
        int slot = (int)sel[img * MAX_DET + t];
        int g = img * TOPK + slot;
        u32 aidx = top_idx[g];
        if (tid < NCLS)      out[loff + tid] = logits[((size_t)img * NA + aidx) * NCLS + tid];
        else if (tid < 84)   out[detoff + (tid - 80)] = boxk[(size_t)g * 4 + (tid - 80)];
        else if (tid == 84)  out[detoff + 4] = top_score[g];
        else if (tid == 85)  out[detoff + 5] = clsf[g];
        else if (tid == 86)  out[voff] = 1.0f;
    } else {
        if (tid < NCLS)      out[loff + tid] = 0.0f;
        else if (tid < 86)   out[detoff + (tid - 80)] = 0.0f;
        else if (tid == 86)  out[voff] = 0.0f;
    }
}

extern "C" void kernel_launch(void* const* d_in, const int* in_sizes, int n_in,
                              void* d_out, int out_size, void* d_ws, size_t ws_size,
                              hipStream_t stream) {
    const float* pred = (const float*)d_in[0];
    const float* logits = (const float*)d_in[1];
    float* out = (float*)d_out;
    const int B = out_size / (MAX_DET * (6 + 1 + NCLS));   // 16
    const int NA = in_sizes[0] / (B * ROW);                // 25200

    char* p = (char*)d_ws;
    auto alloc = [&](size_t bytes) -> void* {
        void* r = (void*)p;
        p += (bytes + 255) & ~(size_t)255;
        return r;
    };
    u32* key       = (u32*)alloc((size_t)B * NA * 4);
    u32* cls       = (u32*)alloc((size_t)B * NA * 4);
    u32* top_idx   = (u32*)alloc((size_t)B * TOPK * 4);
    float* top_scr = (float*)alloc((size_t)B * TOPK * 4);
    float* boxk    = (float*)alloc((size_t)B * TOPK * 16);
    float* nmsbox  = (float*)alloc((size_t)B * TOPK * 16);
    float* clsf    = (float*)alloc((size_t)B * TOPK * 4);
    u64* mask      = (u64*)alloc((size_t)B * TOPK * 16 * 8);
    u32* sel       = (u32*)alloc((size_t)B * MAX_DET * 4);
    u32* selcnt    = (u32*)alloc((size_t)B * 4);

    k_score<<<dim3((NA + APB - 1) / APB, B), 256, 0, stream>>>(pred, key, cls, NA);
    k_topk<<<dim3(B), 1024, 0, stream>>>(key, top_idx, top_scr, NA);
    k_prep<<<dim3(TOPK / 256, B), 256, 0, stream>>>(pred, cls, top_idx, boxk, nmsbox, clsf, NA);
    k_mask<<<dim3(TOPK / 64, B), 1024, 0, stream>>>(nmsbox, mask);
    k_nms<<<dim3(B), 64, 0, stream>>>(mask, top_scr, sel, selcnt);
    k_out<<<dim3(MAX_DET, B), 128, 0, stream>>>(logits, top_idx, top_scr, boxk, clsf,
                                                sel, selcnt, out, NA, B);
}